// Round 4
// baseline (299.644 us; speedup 1.0000x reference)
//
#include <hip/hip_runtime.h>
#include <hip/hip_cooperative_groups.h>

namespace cg = cooperative_groups;

// ---------------------------------------------------------------------------
// keypoint_embedding, R4: single cooperative kernel, 5 grid syncs.
//   S1: inline embed (LDS) + GEMM1 -> emb1b(1024,256) bf16    [64 tiles]
//   S2: GEMM2 -> emb2b(1024,512)                              [128 tiles]
//   S3: GEMM3 -> emb3b(1024,1024)                             [256 tiles]
//   S4: GEMM4 -> AB(1024,1024) fp32 (w1a|w1b split folded)    [256 tiles]
//   S5: pairmean -> msum(16,512) (no atomics)                 [256 units]
//   S6: final   -> out(16,2048)                               [512 units, x2]
// Weights converted fp32->bf16 inline during LDS staging (no conv stage).
// GEMM: 64x64 block tile, 4 waves 2x2, wave tile 32x32 (2x2 mfma 16x16x32).
// ---------------------------------------------------------------------------

typedef __attribute__((ext_vector_type(8))) short s16x8;
typedef __attribute__((ext_vector_type(8))) unsigned short u16x8;
typedef __attribute__((ext_vector_type(4))) float f32x4;

static __device__ __forceinline__ unsigned short f2bf(float f) {
    unsigned u = __float_as_uint(f);
    u += 0x7fff + ((u >> 16) & 1);   // round-to-nearest-even
    return (unsigned short)(u >> 16);
}
static __device__ __forceinline__ u16x8 cvt8(float4 a, float4 b) {
    u16x8 r;
    r[0] = f2bf(a.x); r[1] = f2bf(a.y); r[2] = f2bf(a.z); r[3] = f2bf(a.w);
    r[4] = f2bf(b.x); r[5] = f2bf(b.y); r[6] = f2bf(b.z); r[7] = f2bf(b.w);
    return r;
}

struct P {
    const float *x, *e1w, *e1b, *e2w, *e2b;
    const float *r1w, *r1b, *r2w, *r2b, *r3w, *r3b;
    const float *w1, *b1, *w2, *b2;
    unsigned short *emb1, *emb2, *emb3;
    float *AB, *msum, *out;
};

#define SMEM_BYTES 40960

// generic MFMA GEMM tile: C[m0:m0+64, n0:n0+64] = act(A @ W^T + bias)
// A bf16 (M,K) row-major; W fp32, row n at (g4 ? w1-split : n*K), cvt inline.
static __device__ __forceinline__ void gemm_tile(
    const unsigned short* __restrict__ A, const float* __restrict__ Wf,
    const float* __restrict__ bias, unsigned short* __restrict__ Cb,
    float* __restrict__ Cf, int K, int N, int m0, int n0,
    int g4, int relu, int t, unsigned char* smem)
{
    unsigned short* As = (unsigned short*)smem;       // 64*72
    unsigned short* Ws = As + 64 * 72;                // 64*72
    int lane = t & 63, wv = t >> 6;
    int wm = (wv >> 1) * 32, wn = (wv & 1) * 32;
    int lr = lane & 15, quad = lane >> 4;
    int r = t >> 2, q = t & 3;

    const unsigned short* arow = A + (size_t)(m0 + r) * K + q * 16;
    int n = n0 + r;
    const float* wrow = g4 ? Wf + (size_t)(n & 511) * 2048 + (n >> 9) * 1024 + q * 16
                           : Wf + (size_t)n * K + q * 16;

    f32x4 acc[2][2] = {};
    for (int k0 = 0; k0 < K; k0 += 64) {
        u16x8 a0 = *(const u16x8*)(arow + k0);
        u16x8 a1 = *(const u16x8*)(arow + k0 + 8);
        float4 w0 = *(const float4*)(wrow + k0);
        float4 w1v = *(const float4*)(wrow + k0 + 4);
        float4 w2v = *(const float4*)(wrow + k0 + 8);
        float4 w3v = *(const float4*)(wrow + k0 + 12);
        __syncthreads();                               // prior iter reads done
        *(u16x8*)(As + r * 72 + q * 16)     = a0;
        *(u16x8*)(As + r * 72 + q * 16 + 8) = a1;
        *(u16x8*)(Ws + r * 72 + q * 16)     = cvt8(w0, w1v);
        *(u16x8*)(Ws + r * 72 + q * 16 + 8) = cvt8(w2v, w3v);
        __syncthreads();
#pragma unroll
        for (int kk = 0; kk < 64; kk += 32) {
            s16x8 af[2], bf[2];
#pragma unroll
            for (int mt = 0; mt < 2; ++mt)
                af[mt] = *(const s16x8*)(As + (wm + mt * 16 + lr) * 72 + kk + quad * 8);
#pragma unroll
            for (int nt = 0; nt < 2; ++nt)
                bf[nt] = *(const s16x8*)(Ws + (wn + nt * 16 + lr) * 72 + kk + quad * 8);
#pragma unroll
            for (int mt = 0; mt < 2; ++mt)
#pragma unroll
                for (int nt = 0; nt < 2; ++nt)
                    acc[mt][nt] = __builtin_amdgcn_mfma_f32_16x16x32_bf16(
                        af[mt], bf[nt], acc[mt][nt], 0, 0, 0);
        }
    }
#pragma unroll
    for (int mt = 0; mt < 2; ++mt)
#pragma unroll
        for (int nt = 0; nt < 2; ++nt) {
            int col = n0 + wn + nt * 16 + lr;
            float bv = bias ? bias[col] : 0.f;
#pragma unroll
            for (int rr = 0; rr < 4; ++rr) {
                int row = m0 + wm + mt * 16 + quad * 4 + rr;
                float v = acc[mt][nt][rr] + bv;
                if (relu) v = fmaxf(v, 0.f);
                if (Cb) Cb[(size_t)row * N + col] = f2bf(v);
                else    Cf[(size_t)row * N + col] = v;
            }
        }
}

__global__ __launch_bounds__(256, 2) void k_fused(P p)
{
    __shared__ __align__(16) unsigned char smem[SMEM_BYTES];
    cg::grid_group grid = cg::this_grid();
    int t = threadIdx.x, blk = blockIdx.x;

    // ---------------- S1: inline embed + GEMM1 -> emb1 ----------------------
    if (blk < 64) {
        int m0 = (blk >> 2) * 64, n0 = (blk & 3) * 64;
        float* xs   = (float*)smem;                       // 64*16
        float* e1ws = xs + 1024;                          // 384
        float* e2ws = e1ws + 384;                         // 1664
        float* e1bs = e2ws + 1664;                        // 128
        float* e2bs = e1bs + 128;                         // 128
        unsigned short* emb0 = (unsigned short*)(e2bs + 128);  // 64*136 bf16
        unsigned short* Ws   = emb0 + 64 * 136;           // 64*72

        *(float4*)(xs + t * 4) = *(const float4*)(p.x + (size_t)m0 * 16 + t * 4);
        if (t < 96) *(float4*)(e1ws + t * 4) = *(const float4*)(p.e1w + t * 4);
        for (int i = t; i < 416; i += 256)
            *(float4*)(e2ws + i * 4) = *(const float4*)(p.e2w + i * 4);
        if (t < 128) { e1bs[t] = p.e1b[t]; e2bs[t] = p.e2b[t]; }
        __syncthreads();
        for (int idx = t; idx < 8192; idx += 256) {
            int rr = idx >> 7, o = idx & 127;
            const float* xr = xs + rr * 16;
            float s1 = e1bs[o] + xr[0] * e1ws[o * 3] + xr[1] * e1ws[o * 3 + 1]
                               + xr[2] * e1ws[o * 3 + 2];
            float s2 = e2bs[o];
#pragma unroll
            for (int k = 0; k < 13; ++k) s2 += xr[3 + k] * e2ws[o * 13 + k];
            emb0[rr * 136 + o] = f2bf(fmaxf(s1, 0.f) + fmaxf(s2, 0.f));
        }

        int lane = t & 63, wv = t >> 6;
        int wm = (wv >> 1) * 32, wn = (wv & 1) * 32;
        int lr = lane & 15, quad = lane >> 4;
        int r = t >> 2, q = t & 3;
        const float* wrow = p.r1w + (size_t)(n0 + r) * 128 + q * 16;
        f32x4 acc[2][2] = {};
        for (int k0 = 0; k0 < 128; k0 += 64) {
            float4 w0 = *(const float4*)(wrow + k0);
            float4 w1v = *(const float4*)(wrow + k0 + 4);
            float4 w2v = *(const float4*)(wrow + k0 + 8);
            float4 w3v = *(const float4*)(wrow + k0 + 12);
            __syncthreads();
            *(u16x8*)(Ws + r * 72 + q * 16)     = cvt8(w0, w1v);
            *(u16x8*)(Ws + r * 72 + q * 16 + 8) = cvt8(w2v, w3v);
            __syncthreads();
#pragma unroll
            for (int kk = 0; kk < 64; kk += 32) {
                s16x8 af[2], bf[2];
#pragma unroll
                for (int mt = 0; mt < 2; ++mt)
                    af[mt] = *(const s16x8*)(emb0 + (wm + mt * 16 + lr) * 136 + k0 + kk + quad * 8);
#pragma unroll
                for (int nt = 0; nt < 2; ++nt)
                    bf[nt] = *(const s16x8*)(Ws + (wn + nt * 16 + lr) * 72 + kk + quad * 8);
#pragma unroll
                for (int mt = 0; mt < 2; ++mt)
#pragma unroll
                    for (int nt = 0; nt < 2; ++nt)
                        acc[mt][nt] = __builtin_amdgcn_mfma_f32_16x16x32_bf16(
                            af[mt], bf[nt], acc[mt][nt], 0, 0, 0);
            }
        }
#pragma unroll
        for (int mt = 0; mt < 2; ++mt)
#pragma unroll
            for (int nt = 0; nt < 2; ++nt) {
                int col = n0 + wn + nt * 16 + lr;
                float bv = p.r1b[col];
#pragma unroll
                for (int rr = 0; rr < 4; ++rr) {
                    int row = m0 + wm + mt * 16 + quad * 4 + rr;
                    p.emb1[(size_t)row * 256 + col] = f2bf(fmaxf(acc[mt][nt][rr] + bv, 0.f));
                }
            }
    }
    grid.sync();

    // ---------------- S2: GEMM2 -> emb2 -------------------------------------
    if (blk < 128)
        gemm_tile(p.emb1, p.r2w, p.r2b, p.emb2, nullptr, 256, 512,
                  (blk >> 3) * 64, (blk & 7) * 64, 0, 1, t, smem);
    grid.sync();

    // ---------------- S3: GEMM3 -> emb3 -------------------------------------
    gemm_tile(p.emb2, p.r3w, p.r3b, p.emb3, nullptr, 512, 1024,
              (blk >> 4) * 64, (blk & 15) * 64, 0, 1, t, smem);
    grid.sync();

    // ---------------- S4: GEMM4 -> AB fp32 ----------------------------------
    gemm_tile(p.emb3, p.w1, nullptr, nullptr, p.AB, 1024, 1024,
              (blk >> 4) * 64, (blk & 15) * 64, 1, 0, t, smem);
    grid.sync();

    // ---------------- S5: pairmean -> msum ----------------------------------
    {
        int ub = blk >> 4, cc = (blk & 15) * 32;
        float* pA    = (float*)smem;        // 64*32
        float* pB    = pA + 2048;           // 64*32
        float* sb1   = pB + 2048;           // 32
        float* sPart = sb1 + 32;            // 8*32
        int row = t >> 2, coff = (t & 3) * 8;
        const float* src = p.AB + (size_t)(ub * 64 + row) * 1024 + cc + coff;
        *(float4*)(pA + row * 32 + coff)     = *(const float4*)(src);
        *(float4*)(pA + row * 32 + coff + 4) = *(const float4*)(src + 4);
        *(float4*)(pB + row * 32 + coff)     = *(const float4*)(src + 512);
        *(float4*)(pB + row * 32 + coff + 4) = *(const float4*)(src + 516);
        if (t < 32) sb1[t] = p.b1[cc + t];
        __syncthreads();
        int c = t & 31, ii = t >> 5;
        float bv[8];
#pragma unroll
        for (int i = 0; i < 8; ++i) bv[i] = pB[(ii * 8 + i) * 32 + c] + sb1[c];
        float s = 0.f;
        for (int j = 0; j < 64; ++j) {
            float a = pA[j * 32 + c];
#pragma unroll
            for (int i = 0; i < 8; ++i) s += fmaxf(bv[i] + a, 0.f);
        }
        sPart[ii * 32 + c] = s;
        __syncthreads();
        if (t < 32) {
            float tot = 0.f;
#pragma unroll
            for (int i = 0; i < 8; ++i) tot += sPart[i * 32 + t];
            p.msum[ub * 512 + cc + t] = tot;
        }
    }
    grid.sync();

    // ---------------- S6: final -> out --------------------------------------
    {
        float* sm = (float*)smem;           // 512
        for (int u = blk; u < 512; u += 256) {
            int b = u >> 5, oc = (u & 31) * 64;
            __syncthreads();
            if (t < 128) *(float4*)(sm + t * 4) = *(const float4*)(p.msum + b * 512 + t * 4);
            __syncthreads();
            int o = oc + (t >> 2), kq = (t & 3) * 128;
            const float* wr = p.w2 + (size_t)o * 512 + kq;
            float acc = 0.f;
#pragma unroll 8
            for (int k = 0; k < 128; k += 4) {
                float4 w = *(const float4*)(wr + k);
                acc += sm[kq + k] * w.x + sm[kq + k + 1] * w.y
                     + sm[kq + k + 2] * w.z + sm[kq + k + 3] * w.w;
            }
            acc += __shfl_xor(acc, 1);
            acc += __shfl_xor(acc, 2);
            if ((t & 3) == 0) p.out[b * 2048 + o] = acc * (1.f / 4096.f) + p.b2[o];
        }
    }
}

extern "C" void kernel_launch(void* const* d_in, const int* in_sizes, int n_in,
                              void* d_out, int out_size, void* d_ws, size_t ws_size,
                              hipStream_t stream)
{
    P p;
    p.x   = (const float*)d_in[0];
    p.e1w = (const float*)d_in[1];  p.e1b = (const float*)d_in[2];
    p.e2w = (const float*)d_in[3];  p.e2b = (const float*)d_in[4];
    p.r1w = (const float*)d_in[5];  p.r1b = (const float*)d_in[6];
    p.r2w = (const float*)d_in[7];  p.r2b = (const float*)d_in[8];
    p.r3w = (const float*)d_in[9];  p.r3b = (const float*)d_in[10];
    p.w1  = (const float*)d_in[11]; p.b1  = (const float*)d_in[12];
    p.w2  = (const float*)d_in[13]; p.b2  = (const float*)d_in[14];
    p.out = (float*)d_out;

    unsigned short* w = (unsigned short*)d_ws;
    p.emb1 = w;                               // 1024*256 bf16
    p.emb2 = p.emb1 + 1024 * 256;             // 1024*512
    p.emb3 = p.emb2 + 1024 * 512;             // 1024*1024
    p.AB   = (float*)(p.emb3 + 1024 * 1024);  // 1024*1024 fp32
    p.msum = p.AB + 1024 * 1024;              // 16*512

    void* args[] = { &p };
    hipLaunchCooperativeKernel((void*)k_fused, dim3(256), dim3(256), args, 0, stream);
}

// Round 5
// 161.089 us; speedup vs baseline: 1.8601x; 1.8601x over previous
//
#include <hip/hip_runtime.h>

// ---------------------------------------------------------------------------
// keypoint_embedding, R5: 5 stream-ordered kernels (grid.sync was 35us/ea!).
//   K1 embed+GEMM1 -> emb1(1024,256)bf16          [64 blocks]
//   K2 GEMM2       -> emb2(1024,512)bf16          [128 blocks]
//   K3 GEMM3       -> emb3(1024,1024)bf16         [256 blocks]
//   K4 GEMM4+pairmean -> msum(16,512)f32          [128 blocks, AB stays in LDS]
//   K5 final       -> out(16,2048)f32             [128 blocks]
// fp32 weights converted to bf16 inline during LDS staging (no conv pass).
// ---------------------------------------------------------------------------

typedef __attribute__((ext_vector_type(8))) short s16x8;
typedef __attribute__((ext_vector_type(8))) unsigned short u16x8;
typedef __attribute__((ext_vector_type(4))) float f32x4;

static __device__ __forceinline__ unsigned short f2bf(float f) {
    unsigned u = __float_as_uint(f);
    u += 0x7fff + ((u >> 16) & 1);   // round-to-nearest-even
    return (unsigned short)(u >> 16);
}
static __device__ __forceinline__ u16x8 cvt8(float4 a, float4 b) {
    u16x8 r;
    r[0] = f2bf(a.x); r[1] = f2bf(a.y); r[2] = f2bf(a.z); r[3] = f2bf(a.w);
    r[4] = f2bf(b.x); r[5] = f2bf(b.y); r[6] = f2bf(b.z); r[7] = f2bf(b.w);
    return r;
}

// ---- K1: embed (in LDS) + GEMM1 -> emb1 ------------------------------------
__global__ __launch_bounds__(256) void k_embed_gemm1(
    const float* __restrict__ x,
    const float* __restrict__ e1w, const float* __restrict__ e1b,
    const float* __restrict__ e2w, const float* __restrict__ e2b,
    const float* __restrict__ r1w, const float* __restrict__ r1b,
    unsigned short* __restrict__ emb1)
{
    __shared__ float xs[1024];                 // 64 rows x 16
    __shared__ float e1ws[384], e2ws[1664], e1bs[128], e2bs[128];
    __shared__ unsigned short emb0[64 * 136];  // bf16, padded stride
    __shared__ unsigned short Ws[64 * 72];
    int t = threadIdx.x;
    int m0 = blockIdx.x * 64, n0 = blockIdx.y * 64;

    *(float4*)(xs + t * 4) = *(const float4*)(x + (size_t)m0 * 16 + t * 4);
    if (t < 96) *(float4*)(e1ws + t * 4) = *(const float4*)(e1w + t * 4);
    for (int i = t; i < 416; i += 256)
        *(float4*)(e2ws + i * 4) = *(const float4*)(e2w + i * 4);
    if (t < 128) { e1bs[t] = e1b[t]; e2bs[t] = e2b[t]; }
    __syncthreads();
    for (int idx = t; idx < 8192; idx += 256) {
        int rr = idx >> 7, o = idx & 127;
        const float* xr = xs + rr * 16;
        float s1 = e1bs[o] + xr[0] * e1ws[o * 3] + xr[1] * e1ws[o * 3 + 1]
                           + xr[2] * e1ws[o * 3 + 2];
        float s2 = e2bs[o];
#pragma unroll
        for (int k = 0; k < 13; ++k) s2 += xr[3 + k] * e2ws[o * 13 + k];
        emb0[rr * 136 + o] = f2bf(fmaxf(s1, 0.f) + fmaxf(s2, 0.f));
    }

    int lane = t & 63, wv = t >> 6;
    int wm = (wv >> 1) * 32, wn = (wv & 1) * 32;
    int lr = lane & 15, quad = lane >> 4;
    int r = t >> 2, q = (t & 3) * 16;
    const float* wrow = r1w + (size_t)(n0 + r) * 128 + q;
    f32x4 acc[2][2] = {};
    for (int k0 = 0; k0 < 128; k0 += 64) {
        float4 w0 = *(const float4*)(wrow + k0);
        float4 w1v = *(const float4*)(wrow + k0 + 4);
        float4 w2v = *(const float4*)(wrow + k0 + 8);
        float4 w3v = *(const float4*)(wrow + k0 + 12);
        __syncthreads();
        *(u16x8*)(Ws + r * 72 + q)     = cvt8(w0, w1v);
        *(u16x8*)(Ws + r * 72 + q + 8) = cvt8(w2v, w3v);
        __syncthreads();
#pragma unroll
        for (int kk = 0; kk < 64; kk += 32) {
            s16x8 af[2], bf[2];
#pragma unroll
            for (int mt = 0; mt < 2; ++mt)
                af[mt] = *(const s16x8*)(emb0 + (wm + mt * 16 + lr) * 136 + k0 + kk + quad * 8);
#pragma unroll
            for (int nt = 0; nt < 2; ++nt)
                bf[nt] = *(const s16x8*)(Ws + (wn + nt * 16 + lr) * 72 + kk + quad * 8);
#pragma unroll
            for (int mt = 0; mt < 2; ++mt)
#pragma unroll
                for (int nt = 0; nt < 2; ++nt)
                    acc[mt][nt] = __builtin_amdgcn_mfma_f32_16x16x32_bf16(
                        af[mt], bf[nt], acc[mt][nt], 0, 0, 0);
        }
    }
#pragma unroll
    for (int mt = 0; mt < 2; ++mt)
#pragma unroll
        for (int nt = 0; nt < 2; ++nt) {
            int col = n0 + wn + nt * 16 + lr;
            float bv = r1b[col];
#pragma unroll
            for (int rr = 0; rr < 4; ++rr) {
                int row = m0 + wm + mt * 16 + quad * 4 + rr;
                emb1[(size_t)row * 256 + col] = f2bf(fmaxf(acc[mt][nt][rr] + bv, 0.f));
            }
        }
}

// ---- K2/K3: generic bf16 MFMA GEMM, fp32 W converted inline ---------------
// C = relu(A(M,K)bf16 @ W(N,K)^T + bias), 64x64 tile, 4 waves 2x2.
__global__ __launch_bounds__(256) void k_gemm(
    const unsigned short* __restrict__ A, const float* __restrict__ Wf,
    const float* __restrict__ bias, unsigned short* __restrict__ Cb,
    int K, int N)
{
    __shared__ unsigned short As[64 * 72];
    __shared__ unsigned short Ws[64 * 72];
    int t = threadIdx.x;
    int m0 = blockIdx.x * 64, n0 = blockIdx.y * 64;
    int lane = t & 63, wv = t >> 6;
    int wm = (wv >> 1) * 32, wn = (wv & 1) * 32;
    int lr = lane & 15, quad = lane >> 4;
    int r = t >> 2, q = (t & 3) * 16;

    const unsigned short* arow = A + (size_t)(m0 + r) * K + q;
    const float* wrow = Wf + (size_t)(n0 + r) * K + q;

    f32x4 acc[2][2] = {};
    for (int k0 = 0; k0 < K; k0 += 64) {
        u16x8 a0 = *(const u16x8*)(arow + k0);
        u16x8 a1 = *(const u16x8*)(arow + k0 + 8);
        float4 w0 = *(const float4*)(wrow + k0);
        float4 w1v = *(const float4*)(wrow + k0 + 4);
        float4 w2v = *(const float4*)(wrow + k0 + 8);
        float4 w3v = *(const float4*)(wrow + k0 + 12);
        __syncthreads();
        *(u16x8*)(As + r * 72 + q)     = a0;
        *(u16x8*)(As + r * 72 + q + 8) = a1;
        *(u16x8*)(Ws + r * 72 + q)     = cvt8(w0, w1v);
        *(u16x8*)(Ws + r * 72 + q + 8) = cvt8(w2v, w3v);
        __syncthreads();
#pragma unroll
        for (int kk = 0; kk < 64; kk += 32) {
            s16x8 af[2], bf[2];
#pragma unroll
            for (int mt = 0; mt < 2; ++mt)
                af[mt] = *(const s16x8*)(As + (wm + mt * 16 + lr) * 72 + kk + quad * 8);
#pragma unroll
            for (int nt = 0; nt < 2; ++nt)
                bf[nt] = *(const s16x8*)(Ws + (wn + nt * 16 + lr) * 72 + kk + quad * 8);
#pragma unroll
            for (int mt = 0; mt < 2; ++mt)
#pragma unroll
                for (int nt = 0; nt < 2; ++nt)
                    acc[mt][nt] = __builtin_amdgcn_mfma_f32_16x16x32_bf16(
                        af[mt], bf[nt], acc[mt][nt], 0, 0, 0);
        }
    }
#pragma unroll
    for (int mt = 0; mt < 2; ++mt)
#pragma unroll
        for (int nt = 0; nt < 2; ++nt) {
            int col = n0 + wn + nt * 16 + lr;
            float bv = bias[col];
#pragma unroll
            for (int rr = 0; rr < 4; ++rr) {
                int row = m0 + wm + mt * 16 + quad * 4 + rr;
                Cb[(size_t)row * N + col] = f2bf(fmaxf(acc[mt][nt][rr] + bv, 0.f));
            }
        }
}

// ---- K4: GEMM4 (64x128 tile = one batch x {A|B} col pair) + pairmean ------
// block (cb, b): rows = batch b's 64 rows of emb3; cols = w1a rows
// [cb*64,cb*64+64) and w1b rows [cb*64,cb*64+64). AB tile kept in LDS;
// pairmean epilogue writes msum[b, cb*64 : cb*64+64].
__global__ __launch_bounds__(256) void k_gemm4_pair(
    const unsigned short* __restrict__ emb3, const float* __restrict__ w1,
    const float* __restrict__ b1, float* __restrict__ msum)
{
    __shared__ unsigned short As[64 * 72];     //  9216 B
    __shared__ unsigned short Ws[128 * 72];    // 18432 B
    __shared__ float sA[64 * 68];              // 17408 B  A-part, padded
    __shared__ float sB[64 * 68];              // 17408 B  B-part
    int t = threadIdx.x;
    int cb = blockIdx.x, b = blockIdx.y;
    int lane = t & 63, wv = t >> 6;
    int wn = wv * 32;                          // wave covers cols wn..wn+32 of 128
    int lr = lane & 15, quad = lane >> 4;

    int r = t >> 2, q = (t & 3) * 16;          // A staging: row r, cols q..q+15
    const unsigned short* arow = emb3 + (size_t)(b * 64 + r) * 1024 + q;
    int rw = t >> 1, qw = (t & 1) * 32;        // W staging: row rw (0..127)
    const float* wrow = w1 + (size_t)(cb * 64 + (rw & 63)) * 2048
                           + ((rw >= 64) ? 1024 : 0) + qw;

    f32x4 acc[4][2] = {};
    for (int k0 = 0; k0 < 1024; k0 += 64) {
        u16x8 a0 = *(const u16x8*)(arow + k0);
        u16x8 a1 = *(const u16x8*)(arow + k0 + 8);
        float4 f0 = *(const float4*)(wrow + k0);
        float4 f1 = *(const float4*)(wrow + k0 + 4);
        float4 f2 = *(const float4*)(wrow + k0 + 8);
        float4 f3 = *(const float4*)(wrow + k0 + 12);
        float4 f4 = *(const float4*)(wrow + k0 + 16);
        float4 f5 = *(const float4*)(wrow + k0 + 20);
        float4 f6 = *(const float4*)(wrow + k0 + 24);
        float4 f7 = *(const float4*)(wrow + k0 + 28);
        __syncthreads();
        *(u16x8*)(As + r * 72 + q)       = a0;
        *(u16x8*)(As + r * 72 + q + 8)   = a1;
        *(u16x8*)(Ws + rw * 72 + qw)      = cvt8(f0, f1);
        *(u16x8*)(Ws + rw * 72 + qw + 8)  = cvt8(f2, f3);
        *(u16x8*)(Ws + rw * 72 + qw + 16) = cvt8(f4, f5);
        *(u16x8*)(Ws + rw * 72 + qw + 24) = cvt8(f6, f7);
        __syncthreads();
#pragma unroll
        for (int kk = 0; kk < 64; kk += 32) {
            s16x8 af[4], bf[2];
#pragma unroll
            for (int mt = 0; mt < 4; ++mt)
                af[mt] = *(const s16x8*)(As + (mt * 16 + lr) * 72 + kk + quad * 8);
#pragma unroll
            for (int nt = 0; nt < 2; ++nt)
                bf[nt] = *(const s16x8*)(Ws + (wn + nt * 16 + lr) * 72 + kk + quad * 8);
#pragma unroll
            for (int mt = 0; mt < 4; ++mt)
#pragma unroll
                for (int nt = 0; nt < 2; ++nt)
                    acc[mt][nt] = __builtin_amdgcn_mfma_f32_16x16x32_bf16(
                        af[mt], bf[nt], acc[mt][nt], 0, 0, 0);
        }
    }

    // scatter accumulators into LDS AB tile (cols 0..63 -> sA, 64..127 -> sB)
#pragma unroll
    for (int mt = 0; mt < 4; ++mt)
#pragma unroll
        for (int nt = 0; nt < 2; ++nt) {
            int col = wn + nt * 16 + lr;
            float* dst = (col < 64) ? sA : sB;
            int c = col & 63;
#pragma unroll
            for (int rr = 0; rr < 4; ++rr)
                dst[(mt * 16 + quad * 4 + rr) * 68 + c] = acc[mt][nt][rr];
        }
    __syncthreads();

    // pairmean: msum[b, cb*64+c] = sum_{i,j} relu(B[i,c] + A[j,c] + b1[c])
    {
        int c = t & 63, ig = t >> 6;           // 4 i-groups x 16 rows
        float b1c = b1[cb * 64 + c];
        float bv[16];
#pragma unroll
        for (int i = 0; i < 16; ++i) bv[i] = sB[(ig * 16 + i) * 68 + c] + b1c;
        float s = 0.f;
        for (int j = 0; j < 64; ++j) {
            float a = sA[j * 68 + c];
#pragma unroll
            for (int i = 0; i < 16; ++i) s += fmaxf(bv[i] + a, 0.f);
        }
        float* sPart = (float*)As;             // reuse (all As reads done)
        sPart[ig * 64 + c] = s;
        __syncthreads();
        if (t < 64)
            msum[b * 512 + cb * 64 + t] =
                sPart[t] + sPart[64 + t] + sPart[128 + t] + sPart[192 + t];
    }
}

// ---- K5: final projection --------------------------------------------------
__global__ __launch_bounds__(256) void k_final(
    const float* __restrict__ msum, const float* __restrict__ w2,
    const float* __restrict__ b2, float* __restrict__ out)
{
    __shared__ float sm[512];
    int t = threadIdx.x;
    int b = blockIdx.x;
    int o = blockIdx.y * 256 + t;
    sm[t]       = msum[b * 512 + t]       * (1.f / 4096.f);
    sm[t + 256] = msum[b * 512 + 256 + t] * (1.f / 4096.f);
    __syncthreads();
    const float* wr = w2 + (size_t)o * 512;
    float acc = 0.f;
#pragma unroll 8
    for (int c = 0; c < 512; c += 4) {
        float4 w = *(const float4*)(wr + c);
        acc += sm[c] * w.x + sm[c + 1] * w.y + sm[c + 2] * w.z + sm[c + 3] * w.w;
    }
    out[b * 2048 + o] = acc + b2[o];
}

extern "C" void kernel_launch(void* const* d_in, const int* in_sizes, int n_in,
                              void* d_out, int out_size, void* d_ws, size_t ws_size,
                              hipStream_t stream)
{
    const float* x   = (const float*)d_in[0];
    const float* e1w = (const float*)d_in[1];
    const float* e1b = (const float*)d_in[2];
    const float* e2w = (const float*)d_in[3];
    const float* e2b = (const float*)d_in[4];
    const float* r1w = (const float*)d_in[5];
    const float* r1b = (const float*)d_in[6];
    const float* r2w = (const float*)d_in[7];
    const float* r2b = (const float*)d_in[8];
    const float* r3w = (const float*)d_in[9];
    const float* r3b = (const float*)d_in[10];
    const float* w1  = (const float*)d_in[11];
    const float* b1  = (const float*)d_in[12];
    const float* w2  = (const float*)d_in[13];
    const float* b2  = (const float*)d_in[14];
    float* out = (float*)d_out;

    unsigned short* emb1 = (unsigned short*)d_ws;     // 1024*256
    unsigned short* emb2 = emb1 + 1024 * 256;         // 1024*512
    unsigned short* emb3 = emb2 + 1024 * 512;         // 1024*1024
    float* msum = (float*)(emb3 + 1024 * 1024);       // 16*512

    k_embed_gemm1<<<dim3(16, 4), 256, 0, stream>>>(x, e1w, e1b, e2w, e2b,
                                                   r1w, r1b, emb1);
    k_gemm<<<dim3(16, 8),  256, 0, stream>>>(emb1, r2w, r2b, emb2, 256, 512);
    k_gemm<<<dim3(16, 16), 256, 0, stream>>>(emb2, r3w, r3b, emb3, 512, 1024);
    k_gemm4_pair<<<dim3(8, 16), 256, 0, stream>>>(emb3, w1, b1, msum);
    k_final<<<dim3(16, 8), 256, 0, stream>>>(msum, w2, b2, out);
}

// Round 6
// 139.962 us; speedup vs baseline: 2.1409x; 1.1509x over previous
//
#include <hip/hip_runtime.h>

// ---------------------------------------------------------------------------
// keypoint_embedding, R6: 6 stream-ordered kernels.
//   K0 convert r2w/r3w/w1 -> bf16 (w1 relaid: rows 0..511=A, 512..1023=B)
//   K1 embed+GEMM1 -> emb1(1024,256)bf16          [64 blocks]
//   K2 GEMM2       -> emb2(1024,512)bf16          [128 blocks]
//   K3 GEMM3       -> emb3(1024,1024)bf16         [256 blocks]
//   K4 GEMM4+pairmean -> msum(16,512)             [256 blocks: 16 cb x 16 b,
//        64x64 tile = 32 A-cols + 32 B-cols, bf16 operands, AB never leaves LDS]
//   K5 final       -> out(16,2048)                [128 blocks]
// ---------------------------------------------------------------------------

typedef __attribute__((ext_vector_type(8))) short s16x8;
typedef __attribute__((ext_vector_type(8))) unsigned short u16x8;
typedef __attribute__((ext_vector_type(4))) float f32x4;

static __device__ __forceinline__ unsigned short f2bf(float f) {
    unsigned u = __float_as_uint(f);
    u += 0x7fff + ((u >> 16) & 1);   // round-to-nearest-even
    return (unsigned short)(u >> 16);
}
static __device__ __forceinline__ u16x8 cvt8(float4 a, float4 b) {
    u16x8 r;
    r[0] = f2bf(a.x); r[1] = f2bf(a.y); r[2] = f2bf(a.z); r[3] = f2bf(a.w);
    r[4] = f2bf(b.x); r[5] = f2bf(b.y); r[6] = f2bf(b.z); r[7] = f2bf(b.w);
    return r;
}

// ---- K0: weight conversion fp32 -> bf16 ------------------------------------
__global__ __launch_bounds__(256) void k_convw(
    const float* __restrict__ r2w, const float* __restrict__ r3w,
    const float* __restrict__ w1,
    unsigned short* __restrict__ r2wb, unsigned short* __restrict__ r3wb,
    unsigned short* __restrict__ w1b)
{
    const int n1 = 512 * 256, n2 = 1024 * 512;   // then 1024*1024 (w1 relaid)
    int i = (blockIdx.x * 256 + threadIdx.x) * 4;
    float4 v; unsigned short* dst; int j;
    if (i < n1)           { j = i;        v = *(const float4*)(r2w + j); dst = r2wb + j; }
    else if (i < n1 + n2) { j = i - n1;   v = *(const float4*)(r3w + j); dst = r3wb + j; }
    else {
        j = i - n1 - n2;                 // w1b[n][k]: n<512 -> w1[n][k], else w1[n-512][1024+k]
        int n = j >> 10, k = j & 1023;
        v = *(const float4*)(w1 + (size_t)(n & 511) * 2048 + (n >> 9) * 1024 + k);
        dst = w1b + j;
    }
    ushort4 o; o.x = f2bf(v.x); o.y = f2bf(v.y); o.z = f2bf(v.z); o.w = f2bf(v.w);
    *(ushort4*)dst = o;
}

// ---- K1: embed (in LDS) + GEMM1 -> emb1 ------------------------------------
__global__ __launch_bounds__(256) void k_embed_gemm1(
    const float* __restrict__ x,
    const float* __restrict__ e1w, const float* __restrict__ e1b,
    const float* __restrict__ e2w, const float* __restrict__ e2b,
    const float* __restrict__ r1w, const float* __restrict__ r1b,
    unsigned short* __restrict__ emb1)
{
    __shared__ float xs[1024];
    __shared__ float e1ws[384], e2ws[1664], e1bs[128], e2bs[128];
    __shared__ unsigned short emb0[64 * 136];
    __shared__ unsigned short Ws[64 * 72];
    int t = threadIdx.x;
    int m0 = blockIdx.x * 64, n0 = blockIdx.y * 64;

    *(float4*)(xs + t * 4) = *(const float4*)(x + (size_t)m0 * 16 + t * 4);
    if (t < 96) *(float4*)(e1ws + t * 4) = *(const float4*)(e1w + t * 4);
    for (int i = t; i < 416; i += 256)
        *(float4*)(e2ws + i * 4) = *(const float4*)(e2w + i * 4);
    if (t < 128) { e1bs[t] = e1b[t]; e2bs[t] = e2b[t]; }
    __syncthreads();
    for (int idx = t; idx < 8192; idx += 256) {
        int rr = idx >> 7, o = idx & 127;
        const float* xr = xs + rr * 16;
        float s1 = e1bs[o] + xr[0] * e1ws[o * 3] + xr[1] * e1ws[o * 3 + 1]
                           + xr[2] * e1ws[o * 3 + 2];
        float s2 = e2bs[o];
#pragma unroll
        for (int k = 0; k < 13; ++k) s2 += xr[3 + k] * e2ws[o * 13 + k];
        emb0[rr * 136 + o] = f2bf(fmaxf(s1, 0.f) + fmaxf(s2, 0.f));
    }

    int lane = t & 63, wv = t >> 6;
    int wm = (wv >> 1) * 32, wn = (wv & 1) * 32;
    int lr = lane & 15, quad = lane >> 4;
    int r = t >> 2, q = (t & 3) * 16;
    const float* wrow = r1w + (size_t)(n0 + r) * 128 + q;
    f32x4 acc[2][2] = {};
    for (int k0 = 0; k0 < 128; k0 += 64) {
        float4 w0 = *(const float4*)(wrow + k0);
        float4 w1v = *(const float4*)(wrow + k0 + 4);
        float4 w2v = *(const float4*)(wrow + k0 + 8);
        float4 w3v = *(const float4*)(wrow + k0 + 12);
        __syncthreads();
        *(u16x8*)(Ws + r * 72 + q)     = cvt8(w0, w1v);
        *(u16x8*)(Ws + r * 72 + q + 8) = cvt8(w2v, w3v);
        __syncthreads();
#pragma unroll
        for (int kk = 0; kk < 64; kk += 32) {
            s16x8 af[2], bf[2];
#pragma unroll
            for (int mt = 0; mt < 2; ++mt)
                af[mt] = *(const s16x8*)(emb0 + (wm + mt * 16 + lr) * 136 + k0 + kk + quad * 8);
#pragma unroll
            for (int nt = 0; nt < 2; ++nt)
                bf[nt] = *(const s16x8*)(Ws + (wn + nt * 16 + lr) * 72 + kk + quad * 8);
#pragma unroll
            for (int mt = 0; mt < 2; ++mt)
#pragma unroll
                for (int nt = 0; nt < 2; ++nt)
                    acc[mt][nt] = __builtin_amdgcn_mfma_f32_16x16x32_bf16(
                        af[mt], bf[nt], acc[mt][nt], 0, 0, 0);
        }
    }
#pragma unroll
    for (int mt = 0; mt < 2; ++mt)
#pragma unroll
        for (int nt = 0; nt < 2; ++nt) {
            int col = n0 + wn + nt * 16 + lr;
            float bv = r1b[col];
#pragma unroll
            for (int rr = 0; rr < 4; ++rr) {
                int row = m0 + wm + mt * 16 + quad * 4 + rr;
                emb1[(size_t)row * 256 + col] = f2bf(fmaxf(acc[mt][nt][rr] + bv, 0.f));
            }
        }
}

// ---- K2/K3: bf16 MFMA GEMM (both operands bf16) ---------------------------
__global__ __launch_bounds__(256) void k_gemm(
    const unsigned short* __restrict__ A, const unsigned short* __restrict__ W,
    const float* __restrict__ bias, unsigned short* __restrict__ Cb,
    int K, int N)
{
    __shared__ unsigned short As[64 * 72];
    __shared__ unsigned short Ws[64 * 72];
    int t = threadIdx.x;
    int m0 = blockIdx.x * 64, n0 = blockIdx.y * 64;
    int lane = t & 63, wv = t >> 6;
    int wm = (wv >> 1) * 32, wn = (wv & 1) * 32;
    int lr = lane & 15, quad = lane >> 4;
    int r = t >> 2, q = (t & 3) * 16;

    const unsigned short* arow = A + (size_t)(m0 + r) * K + q;
    const unsigned short* wrow = W + (size_t)(n0 + r) * K + q;

    f32x4 acc[2][2] = {};
    for (int k0 = 0; k0 < K; k0 += 64) {
        u16x8 a0 = *(const u16x8*)(arow + k0);
        u16x8 a1 = *(const u16x8*)(arow + k0 + 8);
        u16x8 w0 = *(const u16x8*)(wrow + k0);
        u16x8 w1 = *(const u16x8*)(wrow + k0 + 8);
        __syncthreads();
        *(u16x8*)(As + r * 72 + q)     = a0;
        *(u16x8*)(As + r * 72 + q + 8) = a1;
        *(u16x8*)(Ws + r * 72 + q)     = w0;
        *(u16x8*)(Ws + r * 72 + q + 8) = w1;
        __syncthreads();
#pragma unroll
        for (int kk = 0; kk < 64; kk += 32) {
            s16x8 af[2], bf[2];
#pragma unroll
            for (int mt = 0; mt < 2; ++mt)
                af[mt] = *(const s16x8*)(As + (wm + mt * 16 + lr) * 72 + kk + quad * 8);
#pragma unroll
            for (int nt = 0; nt < 2; ++nt)
                bf[nt] = *(const s16x8*)(Ws + (wn + nt * 16 + lr) * 72 + kk + quad * 8);
#pragma unroll
            for (int mt = 0; mt < 2; ++mt)
#pragma unroll
                for (int nt = 0; nt < 2; ++nt)
                    acc[mt][nt] = __builtin_amdgcn_mfma_f32_16x16x32_bf16(
                        af[mt], bf[nt], acc[mt][nt], 0, 0, 0);
        }
    }
#pragma unroll
    for (int mt = 0; mt < 2; ++mt)
#pragma unroll
        for (int nt = 0; nt < 2; ++nt) {
            int col = n0 + wn + nt * 16 + lr;
            float bv = bias[col];
#pragma unroll
            for (int rr = 0; rr < 4; ++rr) {
                int row = m0 + wm + mt * 16 + quad * 4 + rr;
                Cb[(size_t)row * N + col] = f2bf(fmaxf(acc[mt][nt][rr] + bv, 0.f));
            }
        }
}

// ---- K4: GEMM4 + pairmean, 256 blocks --------------------------------------
// block (cb,b): rows = batch b's 64 emb3 rows; cols = A-cols [cb*32,cb*32+32)
// (w1b rows cb*32..) and B-cols same range (w1b rows 512+cb*32..).
// 64x64 GEMM tile, AB tile stays in LDS, pairmean epilogue -> msum[b, cb*32+...].
__global__ __launch_bounds__(256) void k_gemm4_pair(
    const unsigned short* __restrict__ emb3, const unsigned short* __restrict__ w1b,
    const float* __restrict__ b1, float* __restrict__ msum)
{
    __shared__ unsigned short As[64 * 72];   // 9216 B
    __shared__ unsigned short Ws[64 * 72];   // 9216 B
    __shared__ float sA[64 * 36];            // 9216 B  (A-cols, stride 36)
    __shared__ float sB[64 * 36];            // 9216 B  (B-cols)
    int t = threadIdx.x;
    int cb = blockIdx.x, b = blockIdx.y;
    int c0 = cb * 32;
    int lane = t & 63, wv = t >> 6;
    int wm = (wv >> 1) * 32, wn = (wv & 1) * 32;
    int lr = lane & 15, quad = lane >> 4;
    int r = t >> 2, q = (t & 3) * 16;

    const unsigned short* arow = emb3 + (size_t)(b * 64 + r) * 1024 + q;
    int wrn = (r < 32) ? (c0 + r) : (512 + c0 + r - 32);
    const unsigned short* wrow = w1b + (size_t)wrn * 1024 + q;

    f32x4 acc[2][2] = {};
    for (int k0 = 0; k0 < 1024; k0 += 64) {
        u16x8 a0 = *(const u16x8*)(arow + k0);
        u16x8 a1 = *(const u16x8*)(arow + k0 + 8);
        u16x8 w0 = *(const u16x8*)(wrow + k0);
        u16x8 w1 = *(const u16x8*)(wrow + k0 + 8);
        __syncthreads();
        *(u16x8*)(As + r * 72 + q)     = a0;
        *(u16x8*)(As + r * 72 + q + 8) = a1;
        *(u16x8*)(Ws + r * 72 + q)     = w0;
        *(u16x8*)(Ws + r * 72 + q + 8) = w1;
        __syncthreads();
#pragma unroll
        for (int kk = 0; kk < 64; kk += 32) {
            s16x8 af[2], bf[2];
#pragma unroll
            for (int mt = 0; mt < 2; ++mt)
                af[mt] = *(const s16x8*)(As + (wm + mt * 16 + lr) * 72 + kk + quad * 8);
#pragma unroll
            for (int nt = 0; nt < 2; ++nt)
                bf[nt] = *(const s16x8*)(Ws + (wn + nt * 16 + lr) * 72 + kk + quad * 8);
#pragma unroll
            for (int mt = 0; mt < 2; ++mt)
#pragma unroll
                for (int nt = 0; nt < 2; ++nt)
                    acc[mt][nt] = __builtin_amdgcn_mfma_f32_16x16x32_bf16(
                        af[mt], bf[nt], acc[mt][nt], 0, 0, 0);
        }
    }

    // scatter: tile cols 0..31 -> sA (A part), 32..63 -> sB (B part)
    __syncthreads();
#pragma unroll
    for (int mt = 0; mt < 2; ++mt)
#pragma unroll
        for (int nt = 0; nt < 2; ++nt) {
            int col = wn + nt * 16 + lr;
            float* dst = (col < 32) ? sA : sB;
            int c = col & 31;
#pragma unroll
            for (int rr = 0; rr < 4; ++rr)
                dst[(wm + mt * 16 + quad * 4 + rr) * 36 + c] = acc[mt][nt][rr];
        }
    __syncthreads();

    // pairmean over this 32-col slice: msum[b, c0+c] = sum_{i,j} relu(B[i,c]+A[j,c]+b1)
    {
        int c = t & 31, ig = t >> 5;          // 8 i-groups x 8 rows
        float b1c = b1[c0 + c];
        float bv[8];
#pragma unroll
        for (int i = 0; i < 8; ++i) bv[i] = sB[(ig * 8 + i) * 36 + c] + b1c;
        float s = 0.f;
        for (int j = 0; j < 64; ++j) {
            float a = sA[j * 36 + c];
#pragma unroll
            for (int i = 0; i < 8; ++i) s += fmaxf(bv[i] + a, 0.f);
        }
        float* sPart = (float*)As;            // reuse
        sPart[ig * 32 + c] = s;
        __syncthreads();
        if (t < 32) {
            float tot = 0.f;
#pragma unroll
            for (int i = 0; i < 8; ++i) tot += sPart[i * 32 + t];
            msum[b * 512 + c0 + t] = tot;
        }
    }
}

// ---- K5: final projection --------------------------------------------------
__global__ __launch_bounds__(256) void k_final(
    const float* __restrict__ msum, const float* __restrict__ w2,
    const float* __restrict__ b2, float* __restrict__ out)
{
    __shared__ float sm[512];
    int t = threadIdx.x;
    int b = blockIdx.x;
    int o = blockIdx.y * 256 + t;
    sm[t]       = msum[b * 512 + t]       * (1.f / 4096.f);
    sm[t + 256] = msum[b * 512 + 256 + t] * (1.f / 4096.f);
    __syncthreads();
    const float* wr = w2 + (size_t)o * 512;
    float acc = 0.f;
#pragma unroll 8
    for (int c = 0; c < 512; c += 4) {
        float4 w = *(const float4*)(wr + c);
        acc += sm[c] * w.x + sm[c + 1] * w.y + sm[c + 2] * w.z + sm[c + 3] * w.w;
    }
    out[b * 2048 + o] = acc + b2[o];
}

extern "C" void kernel_launch(void* const* d_in, const int* in_sizes, int n_in,
                              void* d_out, int out_size, void* d_ws, size_t ws_size,
                              hipStream_t stream)
{
    const float* x   = (const float*)d_in[0];
    const float* e1w = (const float*)d_in[1];
    const float* e1b = (const float*)d_in[2];
    const float* e2w = (const float*)d_in[3];
    const float* e2b = (const float*)d_in[4];
    const float* r1w = (const float*)d_in[5];
    const float* r1b = (const float*)d_in[6];
    const float* r2w = (const float*)d_in[7];
    const float* r2b = (const float*)d_in[8];
    const float* r3w = (const float*)d_in[9];
    const float* r3b = (const float*)d_in[10];
    const float* w1  = (const float*)d_in[11];
    const float* b1  = (const float*)d_in[12];
    const float* w2  = (const float*)d_in[13];
    const float* b2  = (const float*)d_in[14];
    float* out = (float*)d_out;

    unsigned short* emb1 = (unsigned short*)d_ws;     // 1024*256
    unsigned short* emb2 = emb1 + 1024 * 256;         // 1024*512
    unsigned short* emb3 = emb2 + 1024 * 512;         // 1024*1024
    unsigned short* r2wb = emb3 + 1024 * 1024;        // 512*256
    unsigned short* r3wb = r2wb + 512 * 256;          // 1024*512
    unsigned short* w1b  = r3wb + 1024 * 512;         // 1024*1024 (relaid)
    float* msum = (float*)(w1b + 1024 * 1024);        // 16*512

    // (131072 + 524288 + 1048576) / 4 / 256 = 1664 blocks
    k_convw<<<1664, 256, 0, stream>>>(r2w, r3w, w1, r2wb, r3wb, w1b);
    k_embed_gemm1<<<dim3(16, 4), 256, 0, stream>>>(x, e1w, e1b, e2w, e2b,
                                                   r1w, r1b, emb1);
    k_gemm<<<dim3(16, 8),  256, 0, stream>>>(emb1, r2wb, r2b, emb2, 256, 512);
    k_gemm<<<dim3(16, 16), 256, 0, stream>>>(emb2, r3wb, r3b, emb3, 512, 1024);
    k_gemm4_pair<<<dim3(16, 16), 256, 0, stream>>>(emb3, w1b, b1, msum);
    k_final<<<dim3(16, 8), 256, 0, stream>>>(msum, w2, b2, out);
}

// Round 7
// 137.653 us; speedup vs baseline: 2.1768x; 1.0168x over previous
//
#include <hip/hip_runtime.h>

// ---------------------------------------------------------------------------
// keypoint_embedding, R7: 5 stream-ordered kernels.
//   K1 [1728 blocks]: blk<64  -> embed+GEMM1 -> emb1(1024,256)bf16
//                     blk>=64 -> convert r2w/r3w/w1 -> bf16 (w1 relaid)
//   K2 GEMM2          -> emb2(1024,512)bf16          [128 blocks]
//   K3 GEMM3          -> emb3(1024,1024)bf16         [256 blocks]
//   K4 GEMM4+pairmean -> msum(16,512)                [256 blocks, AB in LDS]
//   K5 final          -> out(16,2048)                [128 blocks]
// grid.sync rejected (R4: ~32us/sync on 8 XCDs); dispatch tax ~3us/kernel.
// ---------------------------------------------------------------------------

typedef __attribute__((ext_vector_type(8))) short s16x8;
typedef __attribute__((ext_vector_type(8))) unsigned short u16x8;
typedef __attribute__((ext_vector_type(4))) float f32x4;

static __device__ __forceinline__ unsigned short f2bf(float f) {
    unsigned u = __float_as_uint(f);
    u += 0x7fff + ((u >> 16) & 1);   // round-to-nearest-even
    return (unsigned short)(u >> 16);
}
static __device__ __forceinline__ u16x8 cvt8(float4 a, float4 b) {
    u16x8 r;
    r[0] = f2bf(a.x); r[1] = f2bf(a.y); r[2] = f2bf(a.z); r[3] = f2bf(a.w);
    r[4] = f2bf(b.x); r[5] = f2bf(b.y); r[6] = f2bf(b.z); r[7] = f2bf(b.w);
    return r;
}

// ---- K1: embed+GEMM1 (blocks 0..63) | weight conversion (blocks 64..1727) --
__global__ __launch_bounds__(256) void k_embed_gemm1_conv(
    const float* __restrict__ x,
    const float* __restrict__ e1w, const float* __restrict__ e1b,
    const float* __restrict__ e2w, const float* __restrict__ e2b,
    const float* __restrict__ r1w, const float* __restrict__ r1b,
    const float* __restrict__ r2w, const float* __restrict__ r3w,
    const float* __restrict__ w1,
    unsigned short* __restrict__ emb1,
    unsigned short* __restrict__ r2wb, unsigned short* __restrict__ r3wb,
    unsigned short* __restrict__ w1b)
{
    __shared__ float xs[1024];
    __shared__ float e1ws[384], e2ws[1664], e1bs[128], e2bs[128];
    __shared__ unsigned short emb0[64 * 136];
    __shared__ unsigned short Ws[64 * 72];
    int t = threadIdx.x, blk = blockIdx.x;

    if (blk >= 64) {   // ---- weight conversion ----
        const int n1 = 512 * 256, n2 = 1024 * 512;   // then 1024*1024 (w1 relaid)
        int i = ((blk - 64) * 256 + t) * 4;
        float4 v; unsigned short* dst; int j;
        if (i < n1)           { j = i;      v = *(const float4*)(r2w + j); dst = r2wb + j; }
        else if (i < n1 + n2) { j = i - n1; v = *(const float4*)(r3w + j); dst = r3wb + j; }
        else {
            j = i - n1 - n2;  // w1b[n][k]: n<512 -> w1[n][k], else w1[n-512][1024+k]
            int n = j >> 10, k = j & 1023;
            v = *(const float4*)(w1 + (size_t)(n & 511) * 2048 + (n >> 9) * 1024 + k);
            dst = w1b + j;
        }
        ushort4 o; o.x = f2bf(v.x); o.y = f2bf(v.y); o.z = f2bf(v.z); o.w = f2bf(v.w);
        *(ushort4*)dst = o;
        return;
    }

    // ---- embed + GEMM1 ----
    int m0 = (blk >> 2) * 64, n0 = (blk & 3) * 64;

    *(float4*)(xs + t * 4) = *(const float4*)(x + (size_t)m0 * 16 + t * 4);
    if (t < 96) *(float4*)(e1ws + t * 4) = *(const float4*)(e1w + t * 4);
    for (int i = t; i < 416; i += 256)
        *(float4*)(e2ws + i * 4) = *(const float4*)(e2w + i * 4);
    if (t < 128) { e1bs[t] = e1b[t]; e2bs[t] = e2b[t]; }
    __syncthreads();
    for (int idx = t; idx < 8192; idx += 256) {
        int rr = idx >> 7, o = idx & 127;
        const float* xr = xs + rr * 16;
        float s1 = e1bs[o] + xr[0] * e1ws[o * 3] + xr[1] * e1ws[o * 3 + 1]
                           + xr[2] * e1ws[o * 3 + 2];
        float s2 = e2bs[o];
#pragma unroll
        for (int k = 0; k < 13; ++k) s2 += xr[3 + k] * e2ws[o * 13 + k];
        emb0[rr * 136 + o] = f2bf(fmaxf(s1, 0.f) + fmaxf(s2, 0.f));
    }

    int lane = t & 63, wv = t >> 6;
    int wm = (wv >> 1) * 32, wn = (wv & 1) * 32;
    int lr = lane & 15, quad = lane >> 4;
    int r = t >> 2, q = (t & 3) * 16;
    const float* wrow = r1w + (size_t)(n0 + r) * 128 + q;
    f32x4 acc[2][2] = {};
    for (int k0 = 0; k0 < 128; k0 += 64) {
        float4 w0 = *(const float4*)(wrow + k0);
        float4 w1v = *(const float4*)(wrow + k0 + 4);
        float4 w2v = *(const float4*)(wrow + k0 + 8);
        float4 w3v = *(const float4*)(wrow + k0 + 12);
        __syncthreads();
        *(u16x8*)(Ws + r * 72 + q)     = cvt8(w0, w1v);
        *(u16x8*)(Ws + r * 72 + q + 8) = cvt8(w2v, w3v);
        __syncthreads();
#pragma unroll
        for (int kk = 0; kk < 64; kk += 32) {
            s16x8 af[2], bf[2];
#pragma unroll
            for (int mt = 0; mt < 2; ++mt)
                af[mt] = *(const s16x8*)(emb0 + (wm + mt * 16 + lr) * 136 + k0 + kk + quad * 8);
#pragma unroll
            for (int nt = 0; nt < 2; ++nt)
                bf[nt] = *(const s16x8*)(Ws + (wn + nt * 16 + lr) * 72 + kk + quad * 8);
#pragma unroll
            for (int mt = 0; mt < 2; ++mt)
#pragma unroll
                for (int nt = 0; nt < 2; ++nt)
                    acc[mt][nt] = __builtin_amdgcn_mfma_f32_16x16x32_bf16(
                        af[mt], bf[nt], acc[mt][nt], 0, 0, 0);
        }
    }
#pragma unroll
    for (int mt = 0; mt < 2; ++mt)
#pragma unroll
        for (int nt = 0; nt < 2; ++nt) {
            int col = n0 + wn + nt * 16 + lr;
            float bv = r1b[col];
#pragma unroll
            for (int rr = 0; rr < 4; ++rr) {
                int row = m0 + wm + mt * 16 + quad * 4 + rr;
                emb1[(size_t)row * 256 + col] = f2bf(fmaxf(acc[mt][nt][rr] + bv, 0.f));
            }
        }
}

// ---- K2/K3: bf16 MFMA GEMM (both operands bf16) ---------------------------
__global__ __launch_bounds__(256) void k_gemm(
    const unsigned short* __restrict__ A, const unsigned short* __restrict__ W,
    const float* __restrict__ bias, unsigned short* __restrict__ Cb,
    int K, int N)
{
    __shared__ unsigned short As[64 * 72];
    __shared__ unsigned short Ws[64 * 72];
    int t = threadIdx.x;
    int m0 = blockIdx.x * 64, n0 = blockIdx.y * 64;
    int lane = t & 63, wv = t >> 6;
    int wm = (wv >> 1) * 32, wn = (wv & 1) * 32;
    int lr = lane & 15, quad = lane >> 4;
    int r = t >> 2, q = (t & 3) * 16;

    const unsigned short* arow = A + (size_t)(m0 + r) * K + q;
    const unsigned short* wrow = W + (size_t)(n0 + r) * K + q;

    f32x4 acc[2][2] = {};
    for (int k0 = 0; k0 < K; k0 += 64) {
        u16x8 a0 = *(const u16x8*)(arow + k0);
        u16x8 a1 = *(const u16x8*)(arow + k0 + 8);
        u16x8 w0 = *(const u16x8*)(wrow + k0);
        u16x8 w1 = *(const u16x8*)(wrow + k0 + 8);
        __syncthreads();
        *(u16x8*)(As + r * 72 + q)     = a0;
        *(u16x8*)(As + r * 72 + q + 8) = a1;
        *(u16x8*)(Ws + r * 72 + q)     = w0;
        *(u16x8*)(Ws + r * 72 + q + 8) = w1;
        __syncthreads();
#pragma unroll
        for (int kk = 0; kk < 64; kk += 32) {
            s16x8 af[2], bf[2];
#pragma unroll
            for (int mt = 0; mt < 2; ++mt)
                af[mt] = *(const s16x8*)(As + (wm + mt * 16 + lr) * 72 + kk + quad * 8);
#pragma unroll
            for (int nt = 0; nt < 2; ++nt)
                bf[nt] = *(const s16x8*)(Ws + (wn + nt * 16 + lr) * 72 + kk + quad * 8);
#pragma unroll
            for (int mt = 0; mt < 2; ++mt)
#pragma unroll
                for (int nt = 0; nt < 2; ++nt)
                    acc[mt][nt] = __builtin_amdgcn_mfma_f32_16x16x32_bf16(
                        af[mt], bf[nt], acc[mt][nt], 0, 0, 0);
        }
    }
#pragma unroll
    for (int mt = 0; mt < 2; ++mt)
#pragma unroll
        for (int nt = 0; nt < 2; ++nt) {
            int col = n0 + wn + nt * 16 + lr;
            float bv = bias[col];
#pragma unroll
            for (int rr = 0; rr < 4; ++rr) {
                int row = m0 + wm + mt * 16 + quad * 4 + rr;
                Cb[(size_t)row * N + col] = f2bf(fmaxf(acc[mt][nt][rr] + bv, 0.f));
            }
        }
}

// ---- K4: GEMM4 + pairmean, 256 blocks --------------------------------------
// block (cb,b): rows = batch b's 64 emb3 rows; cols = A-cols [cb*32,cb*32+32)
// (w1b rows cb*32..) and B-cols same range (w1b rows 512+cb*32..).
__global__ __launch_bounds__(256) void k_gemm4_pair(
    const unsigned short* __restrict__ emb3, const unsigned short* __restrict__ w1b,
    const float* __restrict__ b1, float* __restrict__ msum)
{
    __shared__ unsigned short As[64 * 72];
    __shared__ unsigned short Ws[64 * 72];
    __shared__ float sA[64 * 36];
    __shared__ float sB[64 * 36];
    int t = threadIdx.x;
    int cb = blockIdx.x, b = blockIdx.y;
    int c0 = cb * 32;
    int lane = t & 63, wv = t >> 6;
    int wm = (wv >> 1) * 32, wn = (wv & 1) * 32;
    int lr = lane & 15, quad = lane >> 4;
    int r = t >> 2, q = (t & 3) * 16;

    const unsigned short* arow = emb3 + (size_t)(b * 64 + r) * 1024 + q;
    int wrn = (r < 32) ? (c0 + r) : (512 + c0 + r - 32);
    const unsigned short* wrow = w1b + (size_t)wrn * 1024 + q;

    f32x4 acc[2][2] = {};
    for (int k0 = 0; k0 < 1024; k0 += 64) {
        u16x8 a0 = *(const u16x8*)(arow + k0);
        u16x8 a1 = *(const u16x8*)(arow + k0 + 8);
        u16x8 w0 = *(const u16x8*)(wrow + k0);
        u16x8 w1 = *(const u16x8*)(wrow + k0 + 8);
        __syncthreads();
        *(u16x8*)(As + r * 72 + q)     = a0;
        *(u16x8*)(As + r * 72 + q + 8) = a1;
        *(u16x8*)(Ws + r * 72 + q)     = w0;
        *(u16x8*)(Ws + r * 72 + q + 8) = w1;
        __syncthreads();
#pragma unroll
        for (int kk = 0; kk < 64; kk += 32) {
            s16x8 af[2], bf[2];
#pragma unroll
            for (int mt = 0; mt < 2; ++mt)
                af[mt] = *(const s16x8*)(As + (wm + mt * 16 + lr) * 72 + kk + quad * 8);
#pragma unroll
            for (int nt = 0; nt < 2; ++nt)
                bf[nt] = *(const s16x8*)(Ws + (wn + nt * 16 + lr) * 72 + kk + quad * 8);
#pragma unroll
            for (int mt = 0; mt < 2; ++mt)
#pragma unroll
                for (int nt = 0; nt < 2; ++nt)
                    acc[mt][nt] = __builtin_amdgcn_mfma_f32_16x16x32_bf16(
                        af[mt], bf[nt], acc[mt][nt], 0, 0, 0);
        }
    }

    __syncthreads();
#pragma unroll
    for (int mt = 0; mt < 2; ++mt)
#pragma unroll
        for (int nt = 0; nt < 2; ++nt) {
            int col = wn + nt * 16 + lr;
            float* dst = (col < 32) ? sA : sB;
            int c = col & 31;
#pragma unroll
            for (int rr = 0; rr < 4; ++rr)
                dst[(wm + mt * 16 + quad * 4 + rr) * 36 + c] = acc[mt][nt][rr];
        }
    __syncthreads();

    {
        int c = t & 31, ig = t >> 5;          // 8 i-groups x 8 rows
        float b1c = b1[c0 + c];
        float bv[8];
#pragma unroll
        for (int i = 0; i < 8; ++i) bv[i] = sB[(ig * 8 + i) * 36 + c] + b1c;
        float s = 0.f;
        for (int j = 0; j < 64; ++j) {
            float a = sA[j * 36 + c];
#pragma unroll
            for (int i = 0; i < 8; ++i) s += fmaxf(bv[i] + a, 0.f);
        }
        float* sPart = (float*)As;            // reuse
        sPart[ig * 32 + c] = s;
        __syncthreads();
        if (t < 32) {
            float tot = 0.f;
#pragma unroll
            for (int i = 0; i < 8; ++i) tot += sPart[i * 32 + t];
            msum[b * 512 + c0 + t] = tot;
        }
    }
}

// ---- K5: final projection --------------------------------------------------
__global__ __launch_bounds__(256) void k_final(
    const float* __restrict__ msum, const float* __restrict__ w2,
    const float* __restrict__ b2, float* __restrict__ out)
{
    __shared__ float sm[512];
    int t = threadIdx.x;
    int b = blockIdx.x;
    int o = blockIdx.y * 256 + t;
    sm[t]       = msum[b * 512 + t]       * (1.f / 4096.f);
    sm[t + 256] = msum[b * 512 + 256 + t] * (1.f / 4096.f);
    __syncthreads();
    const float* wr = w2 + (size_t)o * 512;
    float acc = 0.f;
#pragma unroll 8
    for (int c = 0; c < 512; c += 4) {
        float4 w = *(const float4*)(wr + c);
        acc += sm[c] * w.x + sm[c + 1] * w.y + sm[c + 2] * w.z + sm[c + 3] * w.w;
    }
    out[b * 2048 + o] = acc + b2[o];
}

extern "C" void kernel_launch(void* const* d_in, const int* in_sizes, int n_in,
                              void* d_out, int out_size, void* d_ws, size_t ws_size,
                              hipStream_t stream)
{
    const float* x   = (const float*)d_in[0];
    const float* e1w = (const float*)d_in[1];
    const float* e1b = (const float*)d_in[2];
    const float* e2w = (const float*)d_in[3];
    const float* e2b = (const float*)d_in[4];
    const float* r1w = (const float*)d_in[5];
    const float* r1b = (const float*)d_in[6];
    const float* r2w = (const float*)d_in[7];
    const float* r2b = (const float*)d_in[8];
    const float* r3w = (const float*)d_in[9];
    const float* r3b = (const float*)d_in[10];
    const float* w1  = (const float*)d_in[11];
    const float* b1  = (const float*)d_in[12];
    const float* w2  = (const float*)d_in[13];
    const float* b2  = (const float*)d_in[14];
    float* out = (float*)d_out;

    unsigned short* emb1 = (unsigned short*)d_ws;     // 1024*256
    unsigned short* emb2 = emb1 + 1024 * 256;         // 1024*512
    unsigned short* emb3 = emb2 + 1024 * 512;         // 1024*1024
    unsigned short* r2wb = emb3 + 1024 * 1024;        // 512*256
    unsigned short* r3wb = r2wb + 512 * 256;          // 1024*512
    unsigned short* w1b  = r3wb + 1024 * 512;         // 1024*1024 (relaid)
    float* msum = (float*)(w1b + 1024 * 1024);        // 16*512

    // K1: 64 embed+gemm1 blocks + 1664 conversion blocks
    k_embed_gemm1_conv<<<1728, 256, 0, stream>>>(x, e1w, e1b, e2w, e2b,
                                                 r1w, r1b, r2w, r3w, w1,
                                                 emb1, r2wb, r3wb, w1b);
    k_gemm<<<dim3(16, 8),  256, 0, stream>>>(emb1, r2wb, r2b, emb2, 256, 512);
    k_gemm<<<dim3(16, 16), 256, 0, stream>>>(emb2, r3wb, r3b, emb3, 512, 1024);
    k_gemm4_pair<<<dim3(16, 16), 256, 0, stream>>>(emb3, w1b, b1, msum);
    k_final<<<dim3(16, 8), 256, 0, stream>>>(msum, w2, b2, out);
}